// Round 1
// baseline (2584.900 us; speedup 1.0000x reference)
//
#include <hip/hip_runtime.h>
#include <math.h>

#define N_TOK 3136
#define CD    256
#define NHD   8
#define DH    32
#define DFFD  1024
#define SCALE 0.17677669529663687f  /* 32^-0.5 */

// ---------------------------------------------------------------- utils
__device__ __forceinline__ unsigned long long sx64(unsigned long long v, int m) {
  unsigned lo = (unsigned)__shfl_xor((int)(unsigned)(v & 0xffffffffull), m, 64);
  unsigned hi = (unsigned)__shfl_xor((int)(unsigned)(v >> 32), m, 64);
  return ((unsigned long long)hi << 32) | lo;
}

__device__ __forceinline__ unsigned f2mono(float v) {
  unsigned b = __float_as_uint(v);
  return (b & 0x80000000u) ? ~b : (b | 0x80000000u);
}

// ------------------------------------------------- transpose (32x32 tiles)
// out[c][r] = in[r][c]; R, C multiples of 32. grid (C/32, R/32), block 256.
__global__ __launch_bounds__(256) void transpose_k(const float* __restrict__ in,
    float* __restrict__ out, int R, int C) {
  __shared__ float ls[32][33];
  const int c0 = blockIdx.x * 32, r0 = blockIdx.y * 32;
  const int tx = threadIdx.x & 31, ty = threadIdx.x >> 5;  // ty 0..7
#pragma unroll
  for (int j = 0; j < 4; ++j) {
    int r = ty + j * 8;
    ls[r][tx] = in[(size_t)(r0 + r) * C + c0 + tx];
  }
  __syncthreads();
#pragma unroll
  for (int j = 0; j < 4; ++j) {
    int cc = ty + j * 8;
    out[(size_t)(c0 + cc) * R + r0 + tx] = ls[tx][cc];
  }
}

// ------------------------------------------------------------- im2col 3x3
// col[pix][ci*9 + ky*3 + kx] = src[ci][y+ky-1][x+kx-1] (zero-padded SAME)
__global__ __launch_bounds__(256) void im2col_k(const float* __restrict__ src,
    float* __restrict__ col) {
  int e = blockIdx.x * 256 + threadIdx.x;     // < 3136*2304 exactly
  int pix = e / 2304;
  int kk = e - pix * 2304;
  int ci = kk / 9;
  int r = kk - ci * 9;
  int ky = r / 3, kx = r - ky * 3;
  int y = pix / 56, x = pix - y * 56;
  int yy = y + ky - 1, xx = x + kx - 1;
  float v = (yy >= 0 && yy < 56 && xx >= 0 && xx < 56)
                ? src[(size_t)ci * 3136 + yy * 56 + xx] : 0.f;
  col[(size_t)e] = v;
}

// --------------------------------------------------------------- GEMM NT
// C[m][n] = sum_k A[m][k]*B[n][k] (+bias[n]) (+relu). M,N %64==0, K %16==0.
// grid (N/64, M/64), block 256.
template <int RELU>
__global__ __launch_bounds__(256) void gemm_nt(const float* __restrict__ A,
    const float* __restrict__ B, const float* __restrict__ bias,
    float* __restrict__ C, int M, int N, int K) {
  __shared__ float As[16][68];
  __shared__ float Bs[16][68];
  const int n0 = blockIdx.x * 64;
  const int m0 = blockIdx.y * 64;
  const int t = threadIdx.x;
  const int tx = t & 15, ty = t >> 4;
  const int lr = t >> 2;           // 0..63
  const int lk = (t & 3) << 2;     // 0,4,8,12
  const float* Ap = A + (size_t)(m0 + lr) * K + lk;
  const float* Bp = B + (size_t)(n0 + lr) * K + lk;
  float acc[4][4] = {};
  for (int k0 = 0; k0 < K; k0 += 16) {
    const float4 a = *(const float4*)(Ap + k0);
    const float4 b = *(const float4*)(Bp + k0);
    __syncthreads();
    As[lk + 0][lr] = a.x; As[lk + 1][lr] = a.y; As[lk + 2][lr] = a.z; As[lk + 3][lr] = a.w;
    Bs[lk + 0][lr] = b.x; Bs[lk + 1][lr] = b.y; Bs[lk + 2][lr] = b.z; Bs[lk + 3][lr] = b.w;
    __syncthreads();
#pragma unroll
    for (int k = 0; k < 16; ++k) {
      const float4 av = *(const float4*)&As[k][ty << 2];
      const float4 bv = *(const float4*)&Bs[k][tx << 2];
      acc[0][0] += av.x * bv.x; acc[0][1] += av.x * bv.y; acc[0][2] += av.x * bv.z; acc[0][3] += av.x * bv.w;
      acc[1][0] += av.y * bv.x; acc[1][1] += av.y * bv.y; acc[1][2] += av.y * bv.z; acc[1][3] += av.y * bv.w;
      acc[2][0] += av.z * bv.x; acc[2][1] += av.z * bv.y; acc[2][2] += av.z * bv.z; acc[2][3] += av.z * bv.w;
      acc[3][0] += av.w * bv.x; acc[3][1] += av.w * bv.y; acc[3][2] += av.w * bv.z; acc[3][3] += av.w * bv.w;
    }
  }
  float4 bb = make_float4(0.f, 0.f, 0.f, 0.f);
  if (bias) bb = *(const float4*)&bias[n0 + (tx << 2)];
#pragma unroll
  for (int i2 = 0; i2 < 4; ++i2) {
    int m = m0 + (ty << 2) + i2;
    float4 r;
    r.x = acc[i2][0] + bb.x; r.y = acc[i2][1] + bb.y;
    r.z = acc[i2][2] + bb.z; r.w = acc[i2][3] + bb.w;
    if (RELU) {
      r.x = fmaxf(r.x, 0.f); r.y = fmaxf(r.y, 0.f);
      r.z = fmaxf(r.z, 0.f); r.w = fmaxf(r.w, 0.f);
    }
    *(float4*)&C[(size_t)m * N + n0 + (tx << 2)] = r;
  }
}

// ------------------------------------------------------------ conv2 (8ch)
// t1: [3136][128] (pix-major from conv1 gemm). gp[pix*8+co] = sigmoid(conv)
__global__ __launch_bounds__(256) void conv2_k(const float* __restrict__ t1,
    const float* __restrict__ w, const float* __restrict__ b,
    float* __restrict__ gp) {
  __shared__ float ws3[9 * 8 * 132];
  const int t = threadIdx.x;
  for (int e = t; e < 9216; e += 256) {
    int r = e >> 10;            // e/1024
    int rem = e & 1023;
    int co = rem >> 7;
    int ci = rem & 127;
    ws3[(r * 8 + co) * 132 + ci] = w[((size_t)co * 128 + ci) * 9 + r];
  }
  __syncthreads();
  const int pix = blockIdx.x * 32 + (t >> 3);
  const int co = t & 7;
  const int y = pix / 56, x = pix - y * 56;
  float acc = b[co];
  for (int ky = 0; ky < 3; ++ky) {
    int yy = y + ky - 1;
    if (yy < 0 || yy >= 56) continue;
    for (int kx = 0; kx < 3; ++kx) {
      int xx = x + kx - 1;
      if (xx < 0 || xx >= 56) continue;
      const float4* tp = (const float4*)&t1[(size_t)(yy * 56 + xx) * 128];
      const float* wp = &ws3[((ky * 3 + kx) * 8 + co) * 132];
#pragma unroll
      for (int c4 = 0; c4 < 32; ++c4) {
        const float4 tv = tp[c4];
        const float4 wv = *(const float4*)&wp[c4 * 4];
        acc += tv.x * wv.x + tv.y * wv.y + tv.z * wv.z + tv.w * wv.w;
      }
    }
  }
  gp[pix * 8 + co] = 1.f / (1.f + expf(-acc));
}

// ------------------------------------------------------------- row ||x||^2
__global__ __launch_bounds__(64) void rowsq_k(const float* __restrict__ x,
                                              float* __restrict__ sq) {
  const int i = blockIdx.x, lane = threadIdx.x;
  const float4 v = ((const float4*)&x[(size_t)i * CD])[lane];
  float s = v.x * v.x + v.y * v.y + v.z * v.z + v.w * v.w;
#pragma unroll
  for (int m = 1; m < 64; m <<= 1) s += __shfl_xor(s, m, 64);
  if (lane == 0) sq[i] = s;
}

// -------------------------------------------------- top-16 NN + in-degree
// One block per row i. d2[j] = (sq[i]-2G[i][j])+sq[j]. 16 iterative
// lexicographic-min extractions (ties -> smaller j), atomicAdd near[j].
__global__ __launch_bounds__(256) void topk_k(const float* __restrict__ G,
    const float* __restrict__ sq, int* __restrict__ near) {
  __shared__ unsigned long long wmin[4];
  const int i = blockIdx.x;
  const int t = threadIdx.x;
  const float sqi = sq[i];
  unsigned long long key[13];
#pragma unroll
  for (int e = 0; e < 13; ++e) {
    int j = t + (e << 8);
    float d2 = INFINITY;
    if (j < N_TOK) d2 = (sqi - 2.f * G[(size_t)i * N_TOK + j]) + sq[j];
    key[e] = ((unsigned long long)f2mono(d2) << 32) | (unsigned)j;
  }
  unsigned long long last = 0ull;
#pragma unroll 1
  for (int r = 0; r < 16; ++r) {
    unsigned long long best = ~0ull;
#pragma unroll
    for (int e = 0; e < 13; ++e) {
      bool ok = (key[e] > last) && (key[e] < best);
      best = ok ? key[e] : best;
    }
#pragma unroll
    for (int m = 1; m < 64; m <<= 1) {
      unsigned long long o = sx64(best, m);
      best = (o < best) ? o : best;
    }
    __syncthreads();                 // protect wmin from previous round reads
    if ((t & 63) == 0) wmin[t >> 6] = best;
    __syncthreads();
    unsigned long long b0 = wmin[0] < wmin[1] ? wmin[0] : wmin[1];
    unsigned long long b1 = wmin[2] < wmin[3] ? wmin[2] : wmin[3];
    best = b0 < b1 ? b0 : b1;
    if (t == 0) atomicAdd(&near[(unsigned)(best & 0xffffffffu)], 1);
    last = best;
  }
}

// ------------------------------------------------------------- max(near)
__global__ __launch_bounds__(256) void nearmax_k(const int* __restrict__ near,
                                                 int* __restrict__ nmax) {
  __shared__ int sm[4];
  const int t = threadIdx.x;
  int m = 0;
  for (int j = t; j < N_TOK; j += 256) m = max(m, near[j]);
#pragma unroll
  for (int s = 1; s < 64; s <<= 1) m = max(m, __shfl_xor(m, s, 64));
  if ((t & 63) == 0) sm[t >> 6] = m;
  __syncthreads();
  if (t == 0) nmax[0] = max(max(sm[0], sm[1]), max(sm[2], sm[3]));
}

// ------------------------------------------------ qk_in = x + emb[ni(near)]
__global__ __launch_bounds__(256) void qkin_k(const float* __restrict__ x,
    const int* __restrict__ near, const int* __restrict__ nmax,
    const float* __restrict__ emb, float* __restrict__ qkin) {
  const int i = blockIdx.x, t = threadIdx.x;
  const float nf = (float)near[i], mf = (float)nmax[0];
  const int ni = (int)(nf / mf * 9.0f);
  qkin[(size_t)i * CD + t] = x[(size_t)i * CD + t] + emb[ni * CD + t];
}

// -------------------------------------------------------- flash attention
// grid (49, 8): 64-query tile per block, head = blockIdx.y. 256 threads:
// thread -> (ii = t>>3 in 0..31 -> rows ii, ii+32 ; qq = t&7 -> 4 cols).
__global__ __launch_bounds__(256) void attn_k(const float* __restrict__ Qm,
    const float* __restrict__ Km, const float* __restrict__ Vm,
    const float* __restrict__ gp, float* __restrict__ Om) {
  const int h = blockIdx.y;
  const int i0 = blockIdx.x * 64;
  const int t = threadIdx.x;
  const int ii = t >> 3;
  const int qq = t & 7;
  const int c0 = qq << 2;
  __shared__ float Kt[32][36];   // [d][j]
  __shared__ float Vs[32][40];   // [j][d]
  __shared__ float Ps[64][36];   // [i][j]
  __shared__ float gpj[32];

  float4 qa[8], qb[8];
  {
    const float* qpa = &Qm[(size_t)(i0 + ii) * CD + h * DH];
    const float* qpb = &Qm[(size_t)(i0 + ii + 32) * CD + h * DH];
#pragma unroll
    for (int u = 0; u < 8; ++u) {
      float4 v = *(const float4*)(qpa + 4 * u);
      qa[u] = make_float4(v.x * SCALE, v.y * SCALE, v.z * SCALE, v.w * SCALE);
      v = *(const float4*)(qpb + 4 * u);
      qb[u] = make_float4(v.x * SCALE, v.y * SCALE, v.z * SCALE, v.w * SCALE);
    }
  }
  const float gpa = gp[(size_t)(i0 + ii) * NHD + h];
  const float gpb = gp[(size_t)(i0 + ii + 32) * NHD + h];
  float ma = -INFINITY, mb = -INFINITY, la = 0.f, lb = 0.f;
  float4 oa = make_float4(0.f, 0.f, 0.f, 0.f);
  float4 ob = make_float4(0.f, 0.f, 0.f, 0.f);

  for (int j0 = 0; j0 < N_TOK; j0 += 32) {
    __syncthreads();
    {
      const float4 kv = *(const float4*)&Km[(size_t)(j0 + ii) * CD + h * DH + c0];
      Kt[c0 + 0][ii] = kv.x; Kt[c0 + 1][ii] = kv.y;
      Kt[c0 + 2][ii] = kv.z; Kt[c0 + 3][ii] = kv.w;
      const float4 vv = *(const float4*)&Vm[(size_t)(j0 + ii) * CD + h * DH + c0];
      *(float4*)&Vs[ii][c0] = vv;
      if (t < 32) gpj[t] = gp[(size_t)(j0 + t) * NHD + h];
    }
    __syncthreads();
    float4 sa = make_float4(0.f, 0.f, 0.f, 0.f);
    float4 sb = make_float4(0.f, 0.f, 0.f, 0.f);
#pragma unroll
    for (int dc = 0; dc < 8; ++dc) {
      const float4 k0 = *(const float4*)&Kt[4 * dc + 0][c0];
      const float4 k1 = *(const float4*)&Kt[4 * dc + 1][c0];
      const float4 k2 = *(const float4*)&Kt[4 * dc + 2][c0];
      const float4 k3 = *(const float4*)&Kt[4 * dc + 3][c0];
      sa.x += qa[dc].x * k0.x + qa[dc].y * k1.x + qa[dc].z * k2.x + qa[dc].w * k3.x;
      sa.y += qa[dc].x * k0.y + qa[dc].y * k1.y + qa[dc].z * k2.y + qa[dc].w * k3.y;
      sa.z += qa[dc].x * k0.z + qa[dc].y * k1.z + qa[dc].z * k2.z + qa[dc].w * k3.z;
      sa.w += qa[dc].x * k0.w + qa[dc].y * k1.w + qa[dc].z * k2.w + qa[dc].w * k3.w;
      sb.x += qb[dc].x * k0.x + qb[dc].y * k1.x + qb[dc].z * k2.x + qb[dc].w * k3.x;
      sb.y += qb[dc].x * k0.y + qb[dc].y * k1.y + qb[dc].z * k2.y + qb[dc].w * k3.y;
      sb.z += qb[dc].x * k0.z + qb[dc].y * k1.z + qb[dc].z * k2.z + qb[dc].w * k3.z;
      sb.w += qb[dc].x * k0.w + qb[dc].y * k1.w + qb[dc].z * k2.w + qb[dc].w * k3.w;
    }
    const float g0 = gpj[c0 + 0], g1 = gpj[c0 + 1], g2 = gpj[c0 + 2], g3 = gpj[c0 + 3];
    sa.x += fabsf(gpa - g0); sa.y += fabsf(gpa - g1);
    sa.z += fabsf(gpa - g2); sa.w += fabsf(gpa - g3);
    sb.x += fabsf(gpb - g0); sb.y += fabsf(gpb - g1);
    sb.z += fabsf(gpb - g2); sb.w += fabsf(gpb - g3);
    // --- online softmax row a
    float mxa = fmaxf(fmaxf(sa.x, sa.y), fmaxf(sa.z, sa.w));
    mxa = fmaxf(mxa, __shfl_xor(mxa, 1, 64));
    mxa = fmaxf(mxa, __shfl_xor(mxa, 2, 64));
    mxa = fmaxf(mxa, __shfl_xor(mxa, 4, 64));
    const float mna = fmaxf(ma, mxa);
    const float ca = __expf(ma - mna);
    float4 pa;
    pa.x = __expf(sa.x - mna); pa.y = __expf(sa.y - mna);
    pa.z = __expf(sa.z - mna); pa.w = __expf(sa.w - mna);
    float psa = pa.x + pa.y + pa.z + pa.w;
    psa += __shfl_xor(psa, 1, 64); psa += __shfl_xor(psa, 2, 64); psa += __shfl_xor(psa, 4, 64);
    la = la * ca + psa; ma = mna;
    oa.x *= ca; oa.y *= ca; oa.z *= ca; oa.w *= ca;
    *(float4*)&Ps[ii][c0] = pa;
    // --- online softmax row b
    float mxb = fmaxf(fmaxf(sb.x, sb.y), fmaxf(sb.z, sb.w));
    mxb = fmaxf(mxb, __shfl_xor(mxb, 1, 64));
    mxb = fmaxf(mxb, __shfl_xor(mxb, 2, 64));
    mxb = fmaxf(mxb, __shfl_xor(mxb, 4, 64));
    const float mnb = fmaxf(mb, mxb);
    const float cb = __expf(mb - mnb);
    float4 pb;
    pb.x = __expf(sb.x - mnb); pb.y = __expf(sb.y - mnb);
    pb.z = __expf(sb.z - mnb); pb.w = __expf(sb.w - mnb);
    float psb = pb.x + pb.y + pb.z + pb.w;
    psb += __shfl_xor(psb, 1, 64); psb += __shfl_xor(psb, 2, 64); psb += __shfl_xor(psb, 4, 64);
    lb = lb * cb + psb; mb = mnb;
    ob.x *= cb; ob.y *= cb; ob.z *= cb; ob.w *= cb;
    *(float4*)&Ps[ii + 32][c0] = pb;
    __syncthreads();
    // --- PV
#pragma unroll
    for (int jc = 0; jc < 8; ++jc) {
      const float4 pva = *(const float4*)&Ps[ii][4 * jc];
      const float4 pvb = *(const float4*)&Ps[ii + 32][4 * jc];
      const float4 v0 = *(const float4*)&Vs[4 * jc + 0][c0];
      const float4 v1 = *(const float4*)&Vs[4 * jc + 1][c0];
      const float4 v2 = *(const float4*)&Vs[4 * jc + 2][c0];
      const float4 v3 = *(const float4*)&Vs[4 * jc + 3][c0];
      oa.x += pva.x * v0.x + pva.y * v1.x + pva.z * v2.x + pva.w * v3.x;
      oa.y += pva.x * v0.y + pva.y * v1.y + pva.z * v2.y + pva.w * v3.y;
      oa.z += pva.x * v0.z + pva.y * v1.z + pva.z * v2.z + pva.w * v3.z;
      oa.w += pva.x * v0.w + pva.y * v1.w + pva.z * v2.w + pva.w * v3.w;
      ob.x += pvb.x * v0.x + pvb.y * v1.x + pvb.z * v2.x + pvb.w * v3.x;
      ob.y += pvb.x * v0.y + pvb.y * v1.y + pvb.z * v2.y + pvb.w * v3.y;
      ob.z += pvb.x * v0.z + pvb.y * v1.z + pvb.z * v2.z + pvb.w * v3.z;
      ob.w += pvb.x * v0.w + pvb.y * v1.w + pvb.z * v2.w + pvb.w * v3.w;
    }
  }
  const float ra = 1.f / la, rb = 1.f / lb;
  float4 w0 = make_float4(oa.x * ra, oa.y * ra, oa.z * ra, oa.w * ra);
  *(float4*)&Om[(size_t)(i0 + ii) * CD + h * DH + c0] = w0;
  float4 w1 = make_float4(ob.x * rb, ob.y * rb, ob.z * rb, ob.w * rb);
  *(float4*)&Om[(size_t)(i0 + ii + 32) * CD + h * DH + c0] = w1;
}

// -------------------------------------------------- LayerNorm (+residual)
__global__ __launch_bounds__(256) void ln_k(const float* __restrict__ xin,
    const float* __restrict__ add, const float* __restrict__ g,
    const float* __restrict__ b, float* __restrict__ xout) {
  __shared__ float red1[4];
  __shared__ float red2[4];
  const int i = blockIdx.x, t = threadIdx.x;
  float v = xin[(size_t)i * CD + t];
  if (add) v += add[(size_t)i * CD + t];
  float s = v;
#pragma unroll
  for (int m = 1; m < 64; m <<= 1) s += __shfl_xor(s, m, 64);
  if ((t & 63) == 0) red1[t >> 6] = s;
  __syncthreads();
  const float mean = (red1[0] + red1[1] + red1[2] + red1[3]) * (1.f / 256.f);
  const float d = v - mean;
  float s2 = d * d;
#pragma unroll
  for (int m = 1; m < 64; m <<= 1) s2 += __shfl_xor(s2, m, 64);
  if ((t & 63) == 0) red2[t >> 6] = s2;
  __syncthreads();
  const float var = (red2[0] + red2[1] + red2[2] + red2[3]) * (1.f / 256.f);
  xout[(size_t)i * CD + t] = d * rsqrtf(var + 1e-5f) * g[t] + b[t];
}

// ---------------------------------------------------------------- launch
extern "C" void kernel_launch(void* const* d_in, const int* in_sizes, int n_in,
                              void* d_out, int out_size, void* d_ws, size_t ws_size,
                              hipStream_t stream) {
  const float* src  = (const float*)d_in[0];
  const float* c1w  = (const float*)d_in[1];
  const float* c1b  = (const float*)d_in[2];
  const float* c2w  = (const float*)d_in[3];
  const float* c2b  = (const float*)d_in[4];
  const float* nemb = (const float*)d_in[5];
  const float* Wq   = (const float*)d_in[6];
  const float* bq   = (const float*)d_in[7];
  const float* Wk   = (const float*)d_in[8];
  const float* bk   = (const float*)d_in[9];
  const float* Wv   = (const float*)d_in[10];
  const float* bv   = (const float*)d_in[11];
  const float* Wo   = (const float*)d_in[12];
  const float* bo   = (const float*)d_in[13];
  const float* W1   = (const float*)d_in[14];
  const float* b1   = (const float*)d_in[15];
  const float* W2   = (const float*)d_in[16];
  const float* b2   = (const float*)d_in[17];
  const float* ln1g = (const float*)d_in[18];
  const float* ln1b = (const float*)d_in[19];
  const float* ln2g = (const float*)d_in[20];
  const float* ln2b = (const float*)d_in[21];
  const float* ng   = (const float*)d_in[22];
  const float* nb   = (const float*)d_in[23];

  float* ws = (float*)d_ws;
  const size_t NC = (size_t)N_TOK * CD;          // 802816
  float* X    = ws;
  float* QKIN = X + NC;
  float* QB   = QKIN + NC;
  float* KB   = QB + NC;
  float* VB   = KB + NC;
  float* O1   = VB + NC;
  float* TMP  = O1 + NC;
  float* FF1  = TMP + NC;                        // 3136*1024
  float* G    = FF1 + (size_t)N_TOK * DFFD;      // 3136*3136 (also im2col)
  float* T1   = G + (size_t)N_TOK * N_TOK;       // 3136*128
  float* GP   = T1 + (size_t)N_TOK * 128;        // 3136*8
  float* SQF  = GP + (size_t)N_TOK * NHD;        // 3136
  int*   NEAR = (int*)(SQF + N_TOK);             // 3136 ints
  int*   NMAX = NEAR + N_TOK;                    // 1 int

  // conv positional encoder: im2col + gemm(relu) + conv2(sigmoid)
  im2col_k<<<28224, 256, 0, stream>>>(src, G);
  gemm_nt<1><<<dim3(2, 49), 256, 0, stream>>>(G, c1w, c1b, T1, N_TOK, 128, 2304);
  conv2_k<<<98, 256, 0, stream>>>(T1, c2w, c2b, GP);
  // tokens: x[tok][ch] = src[ch][tok]
  transpose_k<<<dim3(98, 8), 256, 0, stream>>>(src, X, 256, N_TOK);

  for (int l = 0; l < 4; ++l) {
    // ---- kNN graph -> near counts
    rowsq_k<<<N_TOK, 64, 0, stream>>>(X, SQF);
    gemm_nt<0><<<dim3(49, 49), 256, 0, stream>>>(X, X, nullptr, G, N_TOK, N_TOK, CD);
    hipMemsetAsync(NEAR, 0, N_TOK * sizeof(int), stream);
    topk_k<<<N_TOK, 256, 0, stream>>>(G, SQF, NEAR);
    nearmax_k<<<1, 256, 0, stream>>>(NEAR, NMAX);
    qkin_k<<<N_TOK, 256, 0, stream>>>(X, NEAR, NMAX, nemb, QKIN);
    // ---- attention
    gemm_nt<0><<<dim3(4, 49), 256, 0, stream>>>(QKIN, Wq + (size_t)l * 65536, bq + l * 256, QB, N_TOK, CD, CD);
    gemm_nt<0><<<dim3(4, 49), 256, 0, stream>>>(QKIN, Wk + (size_t)l * 65536, bk + l * 256, KB, N_TOK, CD, CD);
    gemm_nt<0><<<dim3(4, 49), 256, 0, stream>>>(X,    Wv + (size_t)l * 65536, bv + l * 256, VB, N_TOK, CD, CD);
    attn_k<<<dim3(49, 8), 256, 0, stream>>>(QB, KB, VB, GP, O1);
    gemm_nt<0><<<dim3(4, 49), 256, 0, stream>>>(O1, Wo + (size_t)l * 65536, bo + l * 256, TMP, N_TOK, CD, CD);
    ln_k<<<N_TOK, 256, 0, stream>>>(X, TMP, ln1g + l * 256, ln1b + l * 256, X);
    // ---- FFN
    gemm_nt<1><<<dim3(16, 49), 256, 0, stream>>>(X, W1 + (size_t)l * 262144, b1 + l * 1024, FF1, N_TOK, DFFD, CD);
    gemm_nt<0><<<dim3(4, 49), 256, 0, stream>>>(FF1, W2 + (size_t)l * 262144, b2 + l * 256, TMP, N_TOK, CD, DFFD);
    ln_k<<<N_TOK, 256, 0, stream>>>(X, TMP, ln2g + l * 256, ln2b + l * 256, X);
  }
  // final LN + transpose to [1,C,H,W]
  ln_k<<<N_TOK, 256, 0, stream>>>(X, nullptr, ng, nb, TMP);
  transpose_k<<<dim3(8, 98), 256, 0, stream>>>(TMP, (float*)d_out, N_TOK, 256);
}